// Round 6
// baseline (132.794 us; speedup 1.0000x reference)
//
#include <hip/hip_runtime.h>
#include <hip/hip_bf16.h>

#define BATCH 8
#define SEQ   512
#define DIM   512
#define NL    64

typedef float f32x4 __attribute__((ext_vector_type(4)));

// proj v2 — byte-identical to round 5 (single-variable discipline).
__global__ __launch_bounds__(256) void alab_proj2(
    const float* __restrict__ head, const float* __restrict__ dep,
    const float* __restrict__ W, const float* __restrict__ bias,
    float* __restrict__ hbuf, float* __restrict__ dbuf)
{
    __shared__ float4 srow[16][129];            // 16 x 512 f32, +16B row pad
    const int bid   = blockIdx.x;
    const int hd    = bid & 1;                  // 0 = head->h, 1 = dep->d
    const int itile = (bid >> 1) & 31;
    const int b     = bid >> 6;
    const int i0    = itile * 16;

    const float* src  = hd ? dep  : head;
    float*       dst  = hd ? dbuf : hbuf;
    const int    wofs = hd ? 128  : 0;          // float4 offset into W row

    const float4* s4 = (const float4*)(src + ((size_t)b * SEQ + i0) * DIM);
    #pragma unroll
    for (int u = threadIdx.x; u < 16 * 128; u += 256)
        srow[u >> 7][u & 127] = s4[u];
    __syncthreads();

    const int lane = threadIdx.x & 63;
    const int w    = threadIdx.x >> 6;          // 0..3
    const int i    = lane & 15;
    const int li   = lane >> 4;                 // 0..3
    const int lb   = w * 16 + li * 4;           // l = lb + s

    const f32x4* W4 = (const f32x4*)W;          // [NL][256] f32x4
    f32x4 a0 = {0.f,0.f,0.f,0.f}, a1 = {0.f,0.f,0.f,0.f};
    f32x4 a2 = {0.f,0.f,0.f,0.f}, a3 = {0.f,0.f,0.f,0.f};

    #pragma unroll 4
    for (int k4 = 0; k4 < 128; ++k4) {
        const f32x4 hv = *(const f32x4*)&srow[i][k4];
        const size_t wb = (size_t)lb * 256 + wofs + k4;
        a0 += hv * W4[wb];
        a1 += hv * W4[wb + 256];
        a2 += hv * W4[wb + 512];
        a3 += hv * W4[wb + 768];
    }

    float r[4] = { a0.x + a0.y + a0.z + a0.w,
                   a1.x + a1.y + a1.z + a1.w,
                   a2.x + a2.y + a2.z + a2.w,
                   a3.x + a3.y + a3.z + a3.w };
    #pragma unroll
    for (int s = 0; s < 4; ++s) {
        const int l = lb + s;
        const float v = r[s] + (hd ? 0.f : bias[l]);   // bias folded into h
        dst[((size_t)b * NL + l) * SEQ + i0 + i] = v;
    }
}

// bcast v4: 512 blocks, block = (b,l) tile, ONE CONTIGUOUS 1 MiB span per
// block (R2's store-phase structure: the only variant that hit ~6 TB/s).
// 2 blocks/CU, 8 waves/CU — few, long, sequential write streams instead of
// 8192 interleaved 256KB streams. Inner loop: ds_read_b32 (broadcast) +
// 4 adds + plain global_store_dwordx4; d is loop-invariant in a register.
__global__ __launch_bounds__(256) void alab_bcast4(
    const float* __restrict__ hbuf, const float* __restrict__ dbuf,
    float* __restrict__ out)
{
    __shared__ float sh[SEQ];        // full h row for this (b,l)
    __shared__ f32x4 sd4[SEQ / 4];   // full d row
    const int t  = threadIdx.x;
    const int bl = blockIdx.x;       // b*NL + l, 0..511

    sh[t]                  = hbuf[(size_t)bl * SEQ + t];
    sh[t + 256]            = hbuf[(size_t)bl * SEQ + t + 256];
    ((float*)sd4)[t]       = dbuf[(size_t)bl * SEQ + t];
    ((float*)sd4)[t + 256] = dbuf[(size_t)bl * SEQ + t + 256];
    __syncthreads();

    const int j4 = t & 127;                     // fixed float4 column
    const int rh = t >> 7;                      // row parity (0/1)
    const f32x4 dreg = sd4[j4];                 // loop-invariant
    f32x4* ob = (f32x4*)out + (size_t)bl * SEQ * (SEQ / 4);

    #pragma unroll 8
    for (int ii = 0; ii < SEQ; ii += 2) {
        const int i = ii + rh;
        ob[(size_t)i * (SEQ / 4) + j4] = dreg + sh[i];
    }
}

extern "C" void kernel_launch(void* const* d_in, const int* in_sizes, int n_in,
                              void* d_out, int out_size, void* d_ws, size_t ws_size,
                              hipStream_t stream) {
    const float* head = (const float*)d_in[0];
    const float* dep  = (const float*)d_in[1];
    const float* W    = (const float*)d_in[2];
    const float* bias = (const float*)d_in[3];
    float* out  = (float*)d_out;
    float* hbuf = (float*)d_ws;                          // 1 MiB
    float* dbuf = hbuf + (size_t)BATCH * NL * SEQ;       // 1 MiB

    alab_proj2<<<BATCH * 32 * 2, 256, 0, stream>>>(head, dep, W, bias, hbuf, dbuf);
    alab_bcast4<<<BATCH * NL, 256, 0, stream>>>(hbuf, dbuf, out);
}